// Round 7
// baseline (156.149 us; speedup 1.0000x reference)
//
#include <hip/hip_runtime.h>

// Problem constants
#define BATCH 1024
#define SEQ   336
#define CCH   64
#define ORD   168
#define TT    96
#define OFF   168
#define KP    192            // K padded to 6 chunks of 32
#define RSC   25             // Xs row stride in 16-B chunks (+1 pad)
#define YSTR  9              // Ys per-t stride in floats (8 c + 1 pad)

typedef __attribute__((ext_vector_type(8))) short  short8;    // MFMA bf16 frag
typedef __attribute__((ext_vector_type(8))) unsigned short ushort8;
typedef __attribute__((ext_vector_type(4))) float  floatx4;

#define WT2_ELEMS ((size_t)CCH * 36 * 512)   // packed W frags: 1,179,648 ushorts
#define WS_NEED   (WT2_ELEMS * 2)            // 2.25 MB

__device__ __forceinline__ unsigned short f2bf(float f) {
    union { float f; unsigned u; } v; v.f = f;
    unsigned r = v.u + 0x7FFF + ((v.u >> 16) & 1);   // RNE
    return (unsigned short)(r >> 16);
}

// ===== k1w: pack W[c][o][t] into MFMA B-fragment order (unchanged, proven) =====
__global__ __launch_bounds__(256)
void k1w(const float* __restrict__ W, unsigned short* __restrict__ Wt2)
{
    const int tid = threadIdx.x, l = tid & 63, w = tid >> 6;
    const int wid = blockIdx.x * 4 + w;          // 0..2303 = (c,n,kc)
    const int kc = wid % 6;
    const int n  = (wid / 6) % 6;
    const int c  = wid / 36;
    const int m  = l & 15, kg = l >> 4;
    const int t  = n * 16 + m;
    ushort8 u;
    #pragma unroll
    for (int j = 0; j < 8; ++j) {
        int o = kc * 32 + kg * 8 + j;
        float val = (o < ORD) ? W[((size_t)c * ORD + o) * TT + t] : 0.f;
        u[j] = f2bf(val);
    }
    *(ushort8*)(Wt2 + (size_t)wid * 512 + l * 8) = u;
}

// ===== k2f: fused transpose + per-channel bf16 MFMA GEMM =====
// Block = 8 c x 16 b x 96 t, 512 threads = 8 waves, 1 channel per wave.
// GRID MAPPING (round 7): cg = blockIdx%8 -> every block on XCD x works the
// SAME 8 channels. Per-XCD Wt2 working set = 288 KB (stays L2-resident under
// the streaming X), so the 64 btile-blocks per XCD hit L2 for all B-fragment
// re-reads. X: each XCD reads its fixed 32-B channel slice of each row;
// unique HBM fetch once, granule waste confined to the L3->L2 link.
__global__ __launch_bounds__(512, 4)
void k2f(const float* __restrict__ inp, const unsigned short* __restrict__ Wt2,
         const float* __restrict__ bias, float* __restrict__ out)
{
    __shared__ float smem_f[16 * TT * YSTR];          // 55296 B (Ys); Xs aliases it
    unsigned short* Xs = (unsigned short*)smem_f;     // [8c][16b][RSC chunks][8]

    const int tid = threadIdx.x, l = tid & 63, wv = tid >> 6;   // wv = local channel
    const int m = l & 15, kg = l >> 4;
    const int cg    = blockIdx.x & 7;                // == XCD (round-robin dispatch)
    const int btile = blockIdx.x >> 3;               // 0..63
    const int b0 = btile * 16, c0 = cg * 8;

    // ---- stage X: ALL loads first (one drain region), then convert+write.
    // 768 tasks (cq 2, b 16, kchunk 24) over 512 threads.
    floatx4 f[2][8];
    #pragma unroll
    for (int i = 0; i < 2; ++i) {
        int v = tid + i * 512;
        if (v < 768) {
            int cq = v & 1, b = (v >> 1) & 15, kchunk = v >> 5;   // 0..23
            #pragma unroll
            for (int j = 0; j < 8; ++j) {
                int o = kchunk * 8 + j;
                floatx4 z = {0.f, 0.f, 0.f, 0.f};
                f[i][j] = (o < ORD)
                    ? *(const floatx4*)(inp + ((size_t)(b0 + b) * SEQ + OFF + o) * CCH + c0 + cq * 4)
                    : z;
            }
        }
    }
    #pragma unroll
    for (int i = 0; i < 2; ++i) {
        int v = tid + i * 512;
        if (v < 768) {
            int cq = v & 1, b = (v >> 1) & 15, kchunk = v >> 5;
            #pragma unroll
            for (int cc = 0; cc < 4; ++cc) {
                int c = cq * 4 + cc;             // local channel 0..7
                ushort8 u;
                #pragma unroll
                for (int j = 0; j < 8; ++j) u[j] = f2bf(f[i][j][cc]);
                *(ushort8*)(Xs + (((c * 16 + b) * RSC + (kchunk ^ (c & 7))) << 3)) = u;
            }
        }
    }

    // bias for this wave's channel (lane's t = n*16+m)
    float bv[6];
    #pragma unroll
    for (int n = 0; n < 6; ++n)
        bv[n] = bias[(c0 + wv) * TT + n * 16 + m];

    __syncthreads();

    // ---- compute: wave wv handles channel wv: 16b x 96t x 192k
    floatx4 acc[6] = {};
    {
        const int c = wv;
        short8 a[6];
        #pragma unroll
        for (int kc = 0; kc < 6; ++kc) {
            int chunk = (kc * 4 + kg) ^ (c & 7);
            a[kc] = *(const short8*)(Xs + (((c * 16 + m) * RSC + chunk) << 3));
        }
        const unsigned short* Wc = Wt2 + (size_t)(c0 + c) * 36 * 512;
        #pragma unroll
        for (int kc = 0; kc < 6; ++kc) {
            #pragma unroll
            for (int n = 0; n < 6; ++n) {
                short8 bfrag = *(const short8*)(Wc + (size_t)(n * 6 + kc) * 512 + l * 8);
                acc[n] = __builtin_amdgcn_mfma_f32_16x16x32_bf16(a[kc], bfrag, acc[n], 0, 0, 0);
            }
        }
    }

    __syncthreads();   // done reading Xs; reuse as Ys

    // ---- single-shot epilogue: Ys[row][t][c] pad-9 -> 16-B c-runs to global
    float* Ys = smem_f;
    {
        const int c = wv;
        #pragma unroll
        for (int n = 0; n < 6; ++n)
            #pragma unroll
            for (int r = 0; r < 4; ++r) {
                int row = kg * 4 + r;            // D row = local b
                Ys[(row * TT + n * 16 + m) * YSTR + c] = acc[n][r] + bv[n];
            }
    }
    __syncthreads();
    {
        int c4  = tid & 1;
        int te  = (tid >> 1) & 15;
        int row = tid >> 5;                      // 0..15
        #pragma unroll
        for (int s = 0; s < 6; ++s) {
            int tt = te + s * 16;
            floatx4 y = *(const floatx4*)(Ys + (row * TT + tt) * YSTR + c4 * 4);
            *(floatx4*)(out + ((size_t)(b0 + row) * TT + tt) * CCH + c0 + c4 * 4) = y;
        }
    }
}

// ===== fallback (round-2 kernel) if ws too small =====
#define MB  8
#define NT  16
#define KO  8
#define NCH (ORD/KO)
#define WSTRIDE 132
typedef __attribute__((address_space(3))) void* lds_ptr_t;
typedef const __attribute__((address_space(1))) void* gbl_ptr_t;

__global__ __launch_bounds__(256, 4)
void tcl_fallback(const float* __restrict__ inp, const float* __restrict__ W,
                  const float* __restrict__ bias, float* __restrict__ out)
{
    __shared__ float Xsf[MB * KO * CCH];
    __shared__ float Wsf[CCH * WSTRIDE];
    const int tid = threadIdx.x;
    const int c   = tid & 63;
    const int tg  = tid >> 6;
    const int bblk = blockIdx.x & 127;
    const int tblk = blockIdx.x >> 7;
    const int b0 = bblk * MB;
    const int t0 = tblk * NT;
    float acc[MB][4];
    #pragma unroll
    for (int bi = 0; bi < MB; ++bi)
        #pragma unroll
        for (int tj = 0; tj < 4; ++tj) acc[bi][tj] = 0.f;
    for (int ch = 0; ch < NCH; ++ch) {
        const int ob = ch * KO;
        #pragma unroll
        for (int k = 0; k < 4; ++k) {
            int v = tid + k * 256;
            int row = v >> 4, c4 = v & 15;
            int bi = row >> 3, oi = row & 7;
            const float* gp = inp + ((size_t)(b0 + bi) * SEQ + (OFF + ob + oi)) * CCH + c4 * 4;
            __builtin_amdgcn_global_load_lds((gbl_ptr_t)gp, (lds_ptr_t)(Xsf + v * 4), 16, 0, 0);
        }
        float4 wbuf[8];
        #pragma unroll
        for (int k = 0; k < 8; ++k) {
            int v = tid + k * 256;
            int cch = v >> 5, oi = (v >> 2) & 7, t4 = v & 3;
            wbuf[k] = *(const float4*)(W + (size_t)cch * (ORD * TT) + (size_t)(ob + oi) * TT + t0 + t4 * 4);
        }
        #pragma unroll
        for (int k = 0; k < 8; ++k) {
            int v = tid + k * 256;
            int cch = v >> 5, oi = (v >> 2) & 7, t4 = v & 3;
            *(float4*)(Wsf + cch * WSTRIDE + oi * NT + t4 * 4) = wbuf[k];
        }
        __syncthreads();
        #pragma unroll
        for (int oi = 0; oi < KO; ++oi) {
            const float4 wvv = *(const float4*)(Wsf + c * WSTRIDE + oi * NT + tg * 4);
            float xv[MB];
            #pragma unroll
            for (int bi = 0; bi < MB; ++bi) xv[bi] = Xsf[(bi * KO + oi) * CCH + c];
            #pragma unroll
            for (int bi = 0; bi < MB; ++bi) {
                acc[bi][0] += xv[bi] * wvv.x;
                acc[bi][1] += xv[bi] * wvv.y;
                acc[bi][2] += xv[bi] * wvv.z;
                acc[bi][3] += xv[bi] * wvv.w;
            }
        }
        __syncthreads();
    }
    const float4 bvv = *(const float4*)(bias + c * TT + t0 + tg * 4);
    #pragma unroll
    for (int bi = 0; bi < MB; ++bi) {
        size_t base = ((size_t)(b0 + bi) * TT + (t0 + tg * 4)) * CCH + c;
        out[base]           = acc[bi][0] + bvv.x;
        out[base + CCH]     = acc[bi][1] + bvv.y;
        out[base + 2 * CCH] = acc[bi][2] + bvv.z;
        out[base + 3 * CCH] = acc[bi][3] + bvv.w;
    }
}

extern "C" void kernel_launch(void* const* d_in, const int* in_sizes, int n_in,
                              void* d_out, int out_size, void* d_ws, size_t ws_size,
                              hipStream_t stream) {
    const float* inp  = (const float*)d_in[0];   // [1024][336][64]
    const float* W    = (const float*)d_in[1];   // [64][168][96]
    const float* bias = (const float*)d_in[2];   // [64][96]
    float* out = (float*)d_out;                  // [1024][96][64]

    if (ws_size >= WS_NEED) {
        unsigned short* Wt2 = (unsigned short*)d_ws;
        k1w<<<576, 256, 0, stream>>>(W, Wt2);
        k2f<<<512, 512, 0, stream>>>(inp, Wt2, bias, out);
    } else {
        tcl_fallback<<<768, 256, 0, stream>>>(inp, W, bias, out);
    }
}

// Round 8
// 147.332 us; speedup vs baseline: 1.0598x; 1.0598x over previous
//
#include <hip/hip_runtime.h>

// Problem constants
#define BATCH 1024
#define SEQ   336
#define CCH   64
#define ORD   168
#define TT    96
#define OFF   168
#define KP    192            // K padded to 6 chunks of 32
#define RSC   25             // Xs row stride in 16-B chunks (+1 pad)
#define YSTR  12             // Ys per-t stride in floats (8 c + 4 pad, 16-B aligned)

typedef __attribute__((ext_vector_type(8))) short  short8;    // MFMA bf16 frag
typedef __attribute__((ext_vector_type(8))) unsigned short ushort8;
typedef __attribute__((ext_vector_type(4))) float  floatx4;

#define WT2_ELEMS ((size_t)CCH * 36 * 512)   // packed W frags: 1,179,648 ushorts
#define WS_NEED   (WT2_ELEMS * 2)            // 2.25 MB
#define K2_LDS    (8 * 32 * RSC * 16)        // 102400 B (Xs; Ys aliases 73728 B)

__device__ __forceinline__ unsigned short f2bf(float f) {
    union { float f; unsigned u; } v; v.f = f;
    unsigned r = v.u + 0x7FFF + ((v.u >> 16) & 1);   // RNE
    return (unsigned short)(r >> 16);
}

// ===== k1w: pack W[c][o][t] into MFMA B-fragment order (unchanged, proven) =====
__global__ __launch_bounds__(256)
void k1w(const float* __restrict__ W, unsigned short* __restrict__ Wt2)
{
    const int tid = threadIdx.x, l = tid & 63, w = tid >> 6;
    const int wid = blockIdx.x * 4 + w;          // 0..2303 = (c,n,kc)
    const int kc = wid % 6;
    const int n  = (wid / 6) % 6;
    const int c  = wid / 36;
    const int m  = l & 15, kg = l >> 4;
    const int t  = n * 16 + m;
    ushort8 u;
    #pragma unroll
    for (int j = 0; j < 8; ++j) {
        int o = kc * 32 + kg * 8 + j;
        float val = (o < ORD) ? W[((size_t)c * ORD + o) * TT + t] : 0.f;
        u[j] = f2bf(val);
    }
    *(ushort8*)(Wt2 + (size_t)wid * 512 + l * 8) = u;
}

// ===== k2f: fused transpose + per-channel bf16 MFMA GEMM, 32-batch tile =====
// Block = 8 c x 32 b x 96 t, 512 threads = 8 waves, wave = (channel, 32 b).
// 256 blocks -> 1 block/CU (LDS 100 KB). Each B-fragment load feeds TWO MFMAs
// (sub-btiles b0..15 / b16..31): Wt2 re-read traffic halves vs 16-b tile.
// Grid mapping (R6, proven): btile low bits == XCD -> the 8 cg-blocks of a
// btile share an XCD: X lines fetched once, output lines L2-merged.
__global__ __launch_bounds__(512, 2)
void k2f(const float* __restrict__ inp, const unsigned short* __restrict__ Wt2,
         const float* __restrict__ bias, float* __restrict__ out)
{
    extern __shared__ float smem_f[];                 // 102400 B
    unsigned short* Xs = (unsigned short*)smem_f;     // [8c][32b][RSC chunks][8]

    const int tid = threadIdx.x, l = tid & 63, wv = tid >> 6;   // wv = local channel
    const int m = l & 15, kg = l >> 4;
    const int btile = (blockIdx.x & 7) | ((blockIdx.x >> 6) << 3);   // 0..31
    const int cg    = (blockIdx.x >> 3) & 7;
    const int b0 = btile * 32, c0 = cg * 8;

    // ---- stage X: 1536 tasks (cq 2, b 32, kchunk 24) over 512 threads, 3 rounds.
    #pragma unroll
    for (int i = 0; i < 3; ++i) {
        int v = tid + i * 512;
        int cq = v & 1, b = (v >> 1) & 31, kchunk = v >> 6;   // 0..23
        floatx4 f[8];
        #pragma unroll
        for (int j = 0; j < 8; ++j) {
            int o = kchunk * 8 + j;
            floatx4 z = {0.f, 0.f, 0.f, 0.f};
            f[j] = (o < ORD)
                ? *(const floatx4*)(inp + ((size_t)(b0 + b) * SEQ + OFF + o) * CCH + c0 + cq * 4)
                : z;
        }
        #pragma unroll
        for (int cc = 0; cc < 4; ++cc) {
            int c = cq * 4 + cc;             // local channel 0..7
            ushort8 u;
            #pragma unroll
            for (int j = 0; j < 8; ++j) u[j] = f2bf(f[j][cc]);
            *(ushort8*)(Xs + (((c * 32 + b) * RSC + (kchunk ^ (c & 7))) << 3)) = u;
        }
    }

    // bias for this wave's channel (lane's t = n*16+m)
    float bv[6];
    #pragma unroll
    for (int n = 0; n < 6; ++n)
        bv[n] = bias[(c0 + wv) * TT + n * 16 + m];

    __syncthreads();

    // ---- compute: wave wv = channel wv: 32b x 96t x 192k; B-frag reused x2
    floatx4 acc0[6] = {}, acc1[6] = {};
    {
        const unsigned short* Wc = Wt2 + (size_t)(c0 + wv) * 36 * 512;
        #pragma unroll
        for (int kc = 0; kc < 6; ++kc) {
            int chunk = (kc * 4 + kg) ^ (wv & 7);
            short8 a0 = *(const short8*)(Xs + (((wv * 32 + m)      * RSC + chunk) << 3));
            short8 a1 = *(const short8*)(Xs + (((wv * 32 + 16 + m) * RSC + chunk) << 3));
            #pragma unroll
            for (int n = 0; n < 6; ++n) {
                short8 bfrag = *(const short8*)(Wc + (size_t)(n * 6 + kc) * 512 + l * 8);
                acc0[n] = __builtin_amdgcn_mfma_f32_16x16x32_bf16(a0, bfrag, acc0[n], 0, 0, 0);
                acc1[n] = __builtin_amdgcn_mfma_f32_16x16x32_bf16(a1, bfrag, acc1[n], 0, 0, 0);
            }
        }
    }

    __syncthreads();   // done reading Xs; reuse as Ys

    // ---- epilogue: 2 rounds of 16 rows; Ys[row16][t][c] stride-12 (aligned)
    float* Ys = smem_f;
    #pragma unroll
    for (int rnd = 0; rnd < 2; ++rnd) {
        {
            #pragma unroll
            for (int n = 0; n < 6; ++n)
                #pragma unroll
                for (int r = 0; r < 4; ++r) {
                    int row = kg * 4 + r;        // 0..15 within round
                    float val = (rnd == 0 ? acc0[n][r] : acc1[n][r]) + bv[n];
                    Ys[(row * TT + n * 16 + m) * YSTR + wv] = val;
                }
        }
        __syncthreads();
        {
            int c4  = tid & 1;
            int te  = (tid >> 1) & 15;
            int row = tid >> 5;                  // 0..15
            #pragma unroll
            for (int s = 0; s < 6; ++s) {
                int tt = te + s * 16;
                floatx4 y = *(const floatx4*)(Ys + (row * TT + tt) * YSTR + c4 * 4);
                *(floatx4*)(out + ((size_t)(b0 + rnd * 16 + row) * TT + tt) * CCH + c0 + c4 * 4) = y;
            }
        }
        __syncthreads();
    }
}

// ===== fallback (round-2 kernel) if ws too small =====
#define MB  8
#define NT  16
#define KO  8
#define NCH (ORD/KO)
#define WSTRIDE 132
typedef __attribute__((address_space(3))) void* lds_ptr_t;
typedef const __attribute__((address_space(1))) void* gbl_ptr_t;

__global__ __launch_bounds__(256, 4)
void tcl_fallback(const float* __restrict__ inp, const float* __restrict__ W,
                  const float* __restrict__ bias, float* __restrict__ out)
{
    __shared__ float Xsf[MB * KO * CCH];
    __shared__ float Wsf[CCH * WSTRIDE];
    const int tid = threadIdx.x;
    const int c   = tid & 63;
    const int tg  = tid >> 6;
    const int bblk = blockIdx.x & 127;
    const int tblk = blockIdx.x >> 7;
    const int b0 = bblk * MB;
    const int t0 = tblk * NT;
    float acc[MB][4];
    #pragma unroll
    for (int bi = 0; bi < MB; ++bi)
        #pragma unroll
        for (int tj = 0; tj < 4; ++tj) acc[bi][tj] = 0.f;
    for (int ch = 0; ch < NCH; ++ch) {
        const int ob = ch * KO;
        #pragma unroll
        for (int k = 0; k < 4; ++k) {
            int v = tid + k * 256;
            int row = v >> 4, c4 = v & 15;
            int bi = row >> 3, oi = row & 7;
            const float* gp = inp + ((size_t)(b0 + bi) * SEQ + (OFF + ob + oi)) * CCH + c4 * 4;
            __builtin_amdgcn_global_load_lds((gbl_ptr_t)gp, (lds_ptr_t)(Xsf + v * 4), 16, 0, 0);
        }
        float4 wbuf[8];
        #pragma unroll
        for (int k = 0; k < 8; ++k) {
            int v = tid + k * 256;
            int cch = v >> 5, oi = (v >> 2) & 7, t4 = v & 3;
            wbuf[k] = *(const float4*)(W + (size_t)cch * (ORD * TT) + (size_t)(ob + oi) * TT + t0 + t4 * 4);
        }
        #pragma unroll
        for (int k = 0; k < 8; ++k) {
            int v = tid + k * 256;
            int cch = v >> 5, oi = (v >> 2) & 7, t4 = v & 3;
            *(float4*)(Wsf + cch * WSTRIDE + oi * NT + t4 * 4) = wbuf[k];
        }
        __syncthreads();
        #pragma unroll
        for (int oi = 0; oi < KO; ++oi) {
            const float4 wvv = *(const float4*)(Wsf + c * WSTRIDE + oi * NT + tg * 4);
            float xv[MB];
            #pragma unroll
            for (int bi = 0; bi < MB; ++bi) xv[bi] = Xsf[(bi * KO + oi) * CCH + c];
            #pragma unroll
            for (int bi = 0; bi < MB; ++bi) {
                acc[bi][0] += xv[bi] * wvv.x;
                acc[bi][1] += xv[bi] * wvv.y;
                acc[bi][2] += xv[bi] * wvv.z;
                acc[bi][3] += xv[bi] * wvv.w;
            }
        }
        __syncthreads();
    }
    const float4 bvv = *(const float4*)(bias + c * TT + t0 + tg * 4);
    #pragma unroll
    for (int bi = 0; bi < MB; ++bi) {
        size_t base = ((size_t)(b0 + bi) * TT + (t0 + tg * 4)) * CCH + c;
        out[base]           = acc[bi][0] + bvv.x;
        out[base + CCH]     = acc[bi][1] + bvv.y;
        out[base + 2 * CCH] = acc[bi][2] + bvv.z;
        out[base + 3 * CCH] = acc[bi][3] + bvv.w;
    }
}

extern "C" void kernel_launch(void* const* d_in, const int* in_sizes, int n_in,
                              void* d_out, int out_size, void* d_ws, size_t ws_size,
                              hipStream_t stream) {
    const float* inp  = (const float*)d_in[0];   // [1024][336][64]
    const float* W    = (const float*)d_in[1];   // [64][168][96]
    const float* bias = (const float*)d_in[2];   // [64][96]
    float* out = (float*)d_out;                  // [1024][96][64]

    if (ws_size >= WS_NEED) {
        unsigned short* Wt2 = (unsigned short*)d_ws;
        k1w<<<576, 256, 0, stream>>>(W, Wt2);
        k2f<<<256, 512, K2_LDS, stream>>>(inp, Wt2, bias, out);
    } else {
        tcl_fallback<<<768, 256, 0, stream>>>(inp, W, bias, out);
    }
}